// Round 1
// baseline (2061.006 us; speedup 1.0000x reference)
//
#include <hip/hip_runtime.h>

#define SEQ_LEN 262144
#define GROUP 64
#define NGROUP (SEQ_LEN / GROUP)   // 4096
#define HID 256

// ---------- DPP wave64 inclusive prefix sum (gfx9-style scan) ----------
template <int CTRL, int ROWMASK>
__device__ __forceinline__ float dpp_add(float v) {
    int shifted = __builtin_amdgcn_update_dpp(
        0, __builtin_bit_cast(int, v), CTRL, ROWMASK, 0xf, false);
    return v + __builtin_bit_cast(float, shifted);
}

__device__ __forceinline__ float wave_incl_scan(float v) {
    v = dpp_add<0x111, 0xf>(v);  // row_shr:1
    v = dpp_add<0x112, 0xf>(v);  // row_shr:2
    v = dpp_add<0x114, 0xf>(v);  // row_shr:4
    v = dpp_add<0x118, 0xf>(v);  // row_shr:8
    v = dpp_add<0x142, 0xa>(v);  // row_bcast:15 -> rows 1,3
    v = dpp_add<0x143, 0xc>(v);  // row_bcast:31 -> rows 2,3
    return v;
}

__device__ __forceinline__ float readlane_f(float v, int lane) {
    return __builtin_bit_cast(
        float, __builtin_amdgcn_readlane(__builtin_bit_cast(int, v), lane));
}

// tanh(z) = 1 - 2/(1+exp(2z)); exp2 & rcp are 1-ulp HW ops.
// Saturation is handled naturally: exp2(+inf)->inf->rcp 0 -> 1; exp2(-big)->0 -> -1.
__device__ __forceinline__ float ftanh(float z) {
    float e = exp2f(z * 2.885390081777927f);  // 2*log2(e)
    float r = __builtin_amdgcn_rcpf(e + 1.0f);
    return fmaf(-2.0f, r, 1.0f);
}

// ---------- kernel 1: v_t = B @ u_t + bA (parallel, memory-bound) ----------
__global__ __launch_bounds__(256) void vprep_kernel(
    const float* __restrict__ u, const float* __restrict__ B,
    const float* __restrict__ bA, float* __restrict__ v) {
    int s = blockIdx.x * 256 + threadIdx.x;
    float u0 = u[s], u1 = u[SEQ_LEN + s], u2 = u[2 * SEQ_LEN + s];
    v[3 * s + 0] = fmaf(B[0], u0, fmaf(B[1], u1, fmaf(B[2], u2, bA[0])));
    v[3 * s + 1] = fmaf(B[3], u0, fmaf(B[4], u1, fmaf(B[5], u2, bA[1])));
    v[3 * s + 2] = fmaf(B[6], u0, fmaf(B[7], u1, fmaf(B[8], u2, bA[2])));
}

// ---------- kernel 2: serial scan, 1 wave, 64 steps/group, 3-pass corrector ----------
__global__ __launch_bounds__(64) void scan_kernel(
    const float* __restrict__ v,   // [S][3]
    const float* __restrict__ Am,  // [3][3]
    const float* __restrict__ dtp, // scalar
    float* __restrict__ xs) {      // [3][S] (d_out membrane section)
    const int lane = threadIdx.x;
    const float dt = dtp[0];
    const float a00 = Am[0], a01 = Am[1], a02 = Am[2];
    const float a10 = Am[3], a11 = Am[4], a12 = Am[5];
    const float a20 = Am[6], a21 = Am[7], a22 = Am[8];

    float x0 = 0.f, x1 = 0.f, x2 = 0.f;  // group-start state (wave-uniform)

    // depth-4 prefetch ring for v (hides L2/L3 latency off the serial chain)
    float pb0[4], pb1[4], pb2[4];
#pragma unroll
    for (int p = 0; p < 4; ++p) {
        int idx = 3 * (p * GROUP + lane);
        pb0[p] = v[idx]; pb1[p] = v[idx + 1]; pb2[p] = v[idx + 2];
    }

    for (int g = 0; g < NGROUP; g += 4) {
#pragma unroll
        for (int p = 0; p < 4; ++p) {
            const int gg = g + p;
            const float v0 = pb0[p], v1 = pb1[p], v2 = pb2[p];
            // prefetch group gg+4 (dummy-load group 0 at the tail; harmless)
            {
                int ng = (gg + 4 < NGROUP) ? (gg + 4) : 0;
                int fidx = 3 * (ng * GROUP + lane);
                pb0[p] = v[fidx]; pb1[p] = v[fidx + 1]; pb2[p] = v[fidx + 2];
            }

            float y0 = x0, y1 = x1, y2 = x2;  // tanh-input state estimate
            float t0, t1, t2;
#pragma unroll
            for (int pass = 0; pass < 3; ++pass) {
                float z0 = fmaf(a00, y0, fmaf(a01, y1, fmaf(a02, y2, v0)));
                float z1 = fmaf(a10, y0, fmaf(a11, y1, fmaf(a12, y2, v1)));
                float z2 = fmaf(a20, y0, fmaf(a21, y1, fmaf(a22, y2, v2)));
                t0 = ftanh(z0); t1 = ftanh(z1); t2 = ftanh(z2);
                if (pass < 2) {
                    // exclusive prefix -> refined pre-step states
                    float e0 = wave_incl_scan(t0) - t0;
                    float e1 = wave_incl_scan(t1) - t1;
                    float e2 = wave_incl_scan(t2) - t2;
                    y0 = fmaf(dt, e0, x0);
                    y1 = fmaf(dt, e1, x1);
                    y2 = fmaf(dt, e2, x2);
                }
            }
            // inclusive prefix -> post-step states for all 64 timesteps
            float i0 = wave_incl_scan(t0);
            float i1 = wave_incl_scan(t1);
            float i2 = wave_incl_scan(t2);
            float o0 = fmaf(dt, i0, x0);
            float o1 = fmaf(dt, i1, x1);
            float o2 = fmaf(dt, i2, x2);

            const int s = gg * GROUP + lane;
            xs[s] = o0;
            xs[SEQ_LEN + s] = o1;
            xs[2 * SEQ_LEN + s] = o2;

            // hand lane 63's post-step state to the next group (exact value)
            x0 = readlane_f(o0, 63);
            x1 = readlane_f(o1, 63);
            x2 = readlane_f(o2, 63);
        }
    }
}

// ---------- kernel 3: pointwise MLP (parallel) ----------
__global__ __launch_bounds__(256) void mlp_kernel(
    const float* __restrict__ xs,  // [3][S]
    const float* __restrict__ W1,  // [256][3]
    const float* __restrict__ b1v, // [256]
    const float* __restrict__ W2,  // [3][256]
    const float* __restrict__ b2v, // [3]
    float* __restrict__ out) {     // [3][S]
    int s = blockIdx.x * 256 + threadIdx.x;
    float x0 = xs[s], x1 = xs[SEQ_LEN + s], x2 = xs[2 * SEQ_LEN + s];
    float acc0 = 0.f, acc1 = 0.f, acc2 = 0.f;
#pragma unroll 4
    for (int h = 0; h < HID; ++h) {
        float hv = fmaf(W1[3 * h + 0], x0,
                   fmaf(W1[3 * h + 1], x1,
                   fmaf(W1[3 * h + 2], x2, b1v[h])));
        hv = fmaxf(hv, 0.f);
        acc0 = fmaf(W2[h], hv, acc0);
        acc1 = fmaf(W2[HID + h], hv, acc1);
        acc2 = fmaf(W2[2 * HID + h], hv, acc2);
    }
    out[s] = acc0 + b2v[0];
    out[SEQ_LEN + s] = acc1 + b2v[1];
    out[2 * SEQ_LEN + s] = acc2 + b2v[2];
}

extern "C" void kernel_launch(void* const* d_in, const int* in_sizes, int n_in,
                              void* d_out, int out_size, void* d_ws, size_t ws_size,
                              hipStream_t stream) {
    const float* u  = (const float*)d_in[0];
    const float* dt = (const float*)d_in[1];
    const float* A  = (const float*)d_in[2];
    const float* B  = (const float*)d_in[3];
    const float* bA = (const float*)d_in[4];
    const float* W1 = (const float*)d_in[5];
    const float* b1 = (const float*)d_in[6];
    const float* W2 = (const float*)d_in[7];
    const float* b2 = (const float*)d_in[8];

    float* out  = (float*)d_out;           // outputs [3][S]
    float* memb = out + 3 * SEQ_LEN;       // membrane_potentials [3][S]
    float* v    = (float*)d_ws;            // [S][3] scratch, 3 MB

    vprep_kernel<<<SEQ_LEN / 256, 256, 0, stream>>>(u, B, bA, v);
    scan_kernel<<<1, 64, 0, stream>>>(v, A, dt, memb);
    mlp_kernel<<<SEQ_LEN / 256, 256, 0, stream>>>(memb, W1, b1, W2, b2, out);
}

// Round 2
// 1681.675 us; speedup vs baseline: 1.2256x; 1.2256x over previous
//
#include <hip/hip_runtime.h>

#define SEQ_LEN 262144
#define GROUP 64
#define NGROUP (SEQ_LEN / GROUP)   // 4096
#define HID 256
#define PF 8                        // prefetch ring depth (groups)

// 2*log2(e): tanh(z) = 1 - 2/(1+exp2(z*C2LE))
#define C2LE 2.885390081777927f

// ---------- DPP wave64 inclusive prefix sum ----------
template <int CTRL, int ROWMASK>
__device__ __forceinline__ float dpp_add(float v) {
    int shifted = __builtin_amdgcn_update_dpp(
        0, __builtin_bit_cast(int, v), CTRL, ROWMASK, 0xf, false);
    return v + __builtin_bit_cast(float, shifted);
}

__device__ __forceinline__ float wave_incl_scan(float v) {
    v = dpp_add<0x111, 0xf>(v);  // row_shr:1
    v = dpp_add<0x112, 0xf>(v);  // row_shr:2
    v = dpp_add<0x114, 0xf>(v);  // row_shr:4
    v = dpp_add<0x118, 0xf>(v);  // row_shr:8
    v = dpp_add<0x142, 0xa>(v);  // row_bcast:15 -> rows 1,3
    v = dpp_add<0x143, 0xc>(v);  // row_bcast:31 -> rows 2,3
    return v;
}

__device__ __forceinline__ float readlane_f(float v, int lane) {
    return __builtin_bit_cast(
        float, __builtin_amdgcn_readlane(__builtin_bit_cast(int, v), lane));
}

// input pre-scaled by C2LE: t = tanh(z) where zs = C2LE*z
__device__ __forceinline__ float ftanh_s(float zs) {
    float e = __builtin_amdgcn_exp2f(zs);
    float r = __builtin_amdgcn_rcpf(e + 1.0f);
    return fmaf(-2.0f, r, 1.0f);
}

// ---------- kernel 1: v_t = C2LE*(B @ u_t + bA), packed float4 ----------
__global__ __launch_bounds__(256) void vprep_kernel(
    const float* __restrict__ u, const float* __restrict__ B,
    const float* __restrict__ bA, float4* __restrict__ v) {
    int s = blockIdx.x * 256 + threadIdx.x;
    float u0 = u[s], u1 = u[SEQ_LEN + s], u2 = u[2 * SEQ_LEN + s];
    float4 o;
    o.x = C2LE * fmaf(B[0], u0, fmaf(B[1], u1, fmaf(B[2], u2, bA[0])));
    o.y = C2LE * fmaf(B[3], u0, fmaf(B[4], u1, fmaf(B[5], u2, bA[1])));
    o.z = C2LE * fmaf(B[6], u0, fmaf(B[7], u1, fmaf(B[8], u2, bA[2])));
    o.w = 0.f;
    v[s] = o;
}

// ---------- kernel 2: serial scan, 1 wave, 64 steps/group, 3-pass corrector ----------
__global__ __launch_bounds__(64) void scan_kernel(
    const float4* __restrict__ v,  // [S] packed, pre-scaled
    const float* __restrict__ Am,  // [3][3]
    const float* __restrict__ dtp, // scalar
    float* __restrict__ xs) {      // [3][S] (d_out membrane section)
    const int lane = threadIdx.x;
    const float dt = dtp[0];
    // A pre-scaled by C2LE so tanh needs no input multiply
    const float a00 = C2LE * Am[0], a01 = C2LE * Am[1], a02 = C2LE * Am[2];
    const float a10 = C2LE * Am[3], a11 = C2LE * Am[4], a12 = C2LE * Am[5];
    const float a20 = C2LE * Am[6], a21 = C2LE * Am[7], a22 = C2LE * Am[8];

    float x0 = 0.f, x1 = 0.f, x2 = 0.f;  // group-start state (wave-uniform)

    // depth-PF prefetch ring (one dwordx4 per lane per group)
    float4 pb[PF];
#pragma unroll
    for (int p = 0; p < PF; ++p) pb[p] = v[p * GROUP + lane];

    for (int g = 0; g < NGROUP; g += PF) {
#pragma unroll
        for (int p = 0; p < PF; ++p) {
            const int gg = g + p;
            const float v0 = pb[p].x, v1 = pb[p].y, v2 = pb[p].z;
            // prefetch group gg+PF (wrap to 0 at tail; harmless dummy)
            {
                int ng = (gg + PF < NGROUP) ? (gg + PF) : 0;
                pb[p] = v[ng * GROUP + lane];
            }

            float y0 = x0, y1 = x1, y2 = x2;  // tanh-input state estimate
            float t0, t1, t2;
#pragma unroll
            for (int pass = 0; pass < 3; ++pass) {
                float z0 = fmaf(a00, y0, fmaf(a01, y1, fmaf(a02, y2, v0)));
                float z1 = fmaf(a10, y0, fmaf(a11, y1, fmaf(a12, y2, v1)));
                float z2 = fmaf(a20, y0, fmaf(a21, y1, fmaf(a22, y2, v2)));
                t0 = ftanh_s(z0); t1 = ftanh_s(z1); t2 = ftanh_s(z2);
                if (pass < 2) {
                    // exclusive prefix -> refined pre-step states
                    float e0 = wave_incl_scan(t0) - t0;
                    float e1 = wave_incl_scan(t1) - t1;
                    float e2 = wave_incl_scan(t2) - t2;
                    y0 = fmaf(dt, e0, x0);
                    y1 = fmaf(dt, e1, x1);
                    y2 = fmaf(dt, e2, x2);
                }
            }
            // inclusive prefix -> post-step states for all 64 timesteps
            float i0 = wave_incl_scan(t0);
            float i1 = wave_incl_scan(t1);
            float i2 = wave_incl_scan(t2);
            float o0 = fmaf(dt, i0, x0);
            float o1 = fmaf(dt, i1, x1);
            float o2 = fmaf(dt, i2, x2);

            const int s = gg * GROUP + lane;
            xs[s] = o0;
            xs[SEQ_LEN + s] = o1;
            xs[2 * SEQ_LEN + s] = o2;

            // hand lane 63's post-step state to the next group (exact value)
            x0 = readlane_f(o0, 63);
            x1 = readlane_f(o1, 63);
            x2 = readlane_f(o2, 63);
        }
    }
}

// ---------- kernel 3: pointwise MLP (parallel) ----------
__global__ __launch_bounds__(256) void mlp_kernel(
    const float* __restrict__ xs,  // [3][S]
    const float* __restrict__ W1,  // [256][3]
    const float* __restrict__ b1v, // [256]
    const float* __restrict__ W2,  // [3][256]
    const float* __restrict__ b2v, // [3]
    float* __restrict__ out) {     // [3][S]
    int s = blockIdx.x * 256 + threadIdx.x;
    float x0 = xs[s], x1 = xs[SEQ_LEN + s], x2 = xs[2 * SEQ_LEN + s];
    float acc0 = 0.f, acc1 = 0.f, acc2 = 0.f;
#pragma unroll 4
    for (int h = 0; h < HID; ++h) {
        float hv = fmaf(W1[3 * h + 0], x0,
                   fmaf(W1[3 * h + 1], x1,
                   fmaf(W1[3 * h + 2], x2, b1v[h])));
        hv = fmaxf(hv, 0.f);
        acc0 = fmaf(W2[h], hv, acc0);
        acc1 = fmaf(W2[HID + h], hv, acc1);
        acc2 = fmaf(W2[2 * HID + h], hv, acc2);
    }
    out[s] = acc0 + b2v[0];
    out[SEQ_LEN + s] = acc1 + b2v[1];
    out[2 * SEQ_LEN + s] = acc2 + b2v[2];
}

extern "C" void kernel_launch(void* const* d_in, const int* in_sizes, int n_in,
                              void* d_out, int out_size, void* d_ws, size_t ws_size,
                              hipStream_t stream) {
    const float* u  = (const float*)d_in[0];
    const float* dt = (const float*)d_in[1];
    const float* A  = (const float*)d_in[2];
    const float* B  = (const float*)d_in[3];
    const float* bA = (const float*)d_in[4];
    const float* W1 = (const float*)d_in[5];
    const float* b1 = (const float*)d_in[6];
    const float* W2 = (const float*)d_in[7];
    const float* b2 = (const float*)d_in[8];

    float* out  = (float*)d_out;           // outputs [3][S]
    float* memb = out + 3 * SEQ_LEN;       // membrane_potentials [3][S]
    float4* v   = (float4*)d_ws;           // [S] packed scratch, 4 MB

    vprep_kernel<<<SEQ_LEN / 256, 256, 0, stream>>>(u, B, bA, v);
    scan_kernel<<<1, 64, 0, stream>>>(v, A, dt, memb);
    mlp_kernel<<<SEQ_LEN / 256, 256, 0, stream>>>(memb, W1, b1, W2, b2, out);
}

// Round 3
// 1557.210 us; speedup vs baseline: 1.3235x; 1.0799x over previous
//
#include <hip/hip_runtime.h>

#define SEQ_LEN 262144
#define K 256                      // steps per group (one wave)
#define M 4                        // steps per lane (in-lane serial window)
#define NG (SEQ_LEN / K)           // 1024 groups
#define PF 2                       // prefetch ring depth (groups)
#define HID 256
#define C2LE 2.885390081777927f    // 2*log2(e)

// ---------- DPP helpers ----------
template <int CTRL, int RM>
__device__ __forceinline__ float dpp_mov(float oldv, float v) {
    return __builtin_bit_cast(float, __builtin_amdgcn_update_dpp(
        __builtin_bit_cast(int, oldv), __builtin_bit_cast(int, v), CTRL, RM, 0xf, false));
}
template <int CTRL, int RM>
__device__ __forceinline__ float dpp_add(float v) {
    return v + dpp_mov<CTRL, RM>(0.0f, v);
}
__device__ __forceinline__ float wave_incl_scan(float v) {
    v = dpp_add<0x111, 0xf>(v);  // row_shr:1
    v = dpp_add<0x112, 0xf>(v);  // row_shr:2
    v = dpp_add<0x114, 0xf>(v);  // row_shr:4
    v = dpp_add<0x118, 0xf>(v);  // row_shr:8
    v = dpp_add<0x142, 0xa>(v);  // row_bcast:15 -> rows 1,3
    v = dpp_add<0x143, 0xc>(v);  // row_bcast:31 -> rows 2,3
    return v;
}
__device__ __forceinline__ float readlane_f(float v, int lane) {
    return __builtin_bit_cast(
        float, __builtin_amdgcn_readlane(__builtin_bit_cast(int, v), lane));
}

// ---------- affine map (3x3 M, 3 b) ----------
struct Aff { float m[9]; float b[3]; };

// r = n ∘ o  (apply o first, then n): M = n.M * o.M ; b = n.M*o.b + n.b
__device__ __forceinline__ void compose(Aff& r, const Aff& n, const Aff& o) {
#pragma unroll
    for (int i = 0; i < 3; ++i) {
#pragma unroll
        for (int j = 0; j < 3; ++j)
            r.m[3*i+j] = fmaf(n.m[3*i+0], o.m[0+j],
                         fmaf(n.m[3*i+1], o.m[3+j],
                              n.m[3*i+2] * o.m[6+j]));
        r.b[i] = fmaf(n.m[3*i+0], o.b[0],
                 fmaf(n.m[3*i+1], o.b[1],
                 fmaf(n.m[3*i+2], o.b[2], n.b[i])));
    }
}

// one Hillis-Steele level: partner fetched via DPP with identity as `old`
// (masked/OOB lanes compose with identity = no-op). self ∘ partner(older).
template <int CTRL, int RM>
__device__ __forceinline__ void scan_level(Aff& a) {
    Aff p;
    p.m[0] = dpp_mov<CTRL, RM>(1.f, a.m[0]);
    p.m[1] = dpp_mov<CTRL, RM>(0.f, a.m[1]);
    p.m[2] = dpp_mov<CTRL, RM>(0.f, a.m[2]);
    p.m[3] = dpp_mov<CTRL, RM>(0.f, a.m[3]);
    p.m[4] = dpp_mov<CTRL, RM>(1.f, a.m[4]);
    p.m[5] = dpp_mov<CTRL, RM>(0.f, a.m[5]);
    p.m[6] = dpp_mov<CTRL, RM>(0.f, a.m[6]);
    p.m[7] = dpp_mov<CTRL, RM>(0.f, a.m[7]);
    p.m[8] = dpp_mov<CTRL, RM>(1.f, a.m[8]);
    p.b[0] = dpp_mov<CTRL, RM>(0.f, a.b[0]);
    p.b[1] = dpp_mov<CTRL, RM>(0.f, a.b[1]);
    p.b[2] = dpp_mov<CTRL, RM>(0.f, a.b[2]);
    Aff r; compose(r, a, p); a = r;
}

// ---------- kernel 1: w_t = C2LE*(B u_t + bA), packed float4 ----------
__global__ __launch_bounds__(256) void vprep_kernel(
    const float* __restrict__ u, const float* __restrict__ B,
    const float* __restrict__ bA, float4* __restrict__ v) {
    int s = blockIdx.x * 256 + threadIdx.x;
    float u0 = u[s], u1 = u[SEQ_LEN + s], u2 = u[2 * SEQ_LEN + s];
    float4 o;
    o.x = C2LE * fmaf(B[0], u0, fmaf(B[1], u1, fmaf(B[2], u2, bA[0])));
    o.y = C2LE * fmaf(B[3], u0, fmaf(B[4], u1, fmaf(B[5], u2, bA[1])));
    o.z = C2LE * fmaf(B[6], u0, fmaf(B[7], u1, fmaf(B[8], u2, bA[2])));
    o.w = 0.f;
    v[s] = o;
}

// ---------- kernel 2: serial affine-scan, 1 wave, 256 steps/group ----------
__global__ __launch_bounds__(64) void scan_kernel(
    const float4* __restrict__ v,  // [S] C2LE-scaled w
    const float* __restrict__ Am,  // [3][3]
    const float* __restrict__ dtp, // scalar
    float* __restrict__ xs) {      // [3][S]
    const int lane = threadIdx.x;
    const float dt = dtp[0];
    const float invdt3 = 1.0f / (3.0f * dt);
    float a[9], as[9];
#pragma unroll
    for (int i = 0; i < 9; ++i) { a[i] = Am[i]; as[i] = C2LE * Am[i]; }

    float x0 = 0.f, x1 = 0.f, x2 = 0.f;  // group-start state (wave-uniform)

    // prefetch ring: lane j holds M consecutive float4s (64B contiguous)
    float4 rb[PF][M];
#pragma unroll
    for (int p = 0; p < PF; ++p)
#pragma unroll
        for (int i = 0; i < M; ++i)
            rb[p][i] = v[p * K + M * lane + i];

    for (int g = 0; g < NG; g += PF) {
#pragma unroll
        for (int p = 0; p < PF; ++p) {
            const int gg = g + p;
            float4 w[M];
#pragma unroll
            for (int i = 0; i < M; ++i) w[i] = rb[p][i];
            {
                int ng = (gg + PF < NG) ? (gg + PF) : 0;
#pragma unroll
                for (int i = 0; i < M; ++i) rb[p][i] = v[ng * K + M * lane + i];
            }

            // zc = C2LE * A * x_g (wave-uniform)
            float zc0 = fmaf(as[0], x0, fmaf(as[1], x1, as[2] * x2));
            float zc1 = fmaf(as[3], x0, fmaf(as[4], x1, as[5] * x2));
            float zc2 = fmaf(as[6], x0, fmaf(as[7], x1, as[8] * x2));

            // per-step Taylor coefficients around x_g (ONE tanh eval per step)
            float cb[M][3], c1[M][3], cT2[M][3], cT3[M][3];
#pragma unroll
            for (int i = 0; i < M; ++i) {
                float z[3] = { w[i].x + zc0, w[i].y + zc1, w[i].z + zc2 };
#pragma unroll
                for (int c = 0; c < 3; ++c) {
                    float e  = __builtin_amdgcn_exp2f(z[c]);
                    float r  = __builtin_amdgcn_rcpf(e + 1.0f);
                    float t0 = fmaf(-2.0f, r, 1.0f);          // tanh
                    float b  = dt * t0;
                    float cv = fmaf(-b, t0, dt);              // dt*(1-t0^2)
                    float s23 = 0.66666667f * (t0 * t0);      // (2/3)T0^2
                    float pc  = fmaf(-invdt3, cv, s23);       // (2/3)T0^2 - T1/3
                    cb[i][c] = b; c1[i][c] = cv;
                    cT2[i][c] = -t0 * cv;                     // -dt*T0*T1
                    cT3[i][c] = cv * pc;                      // dt*T1*(4T0^2-2T1)/6
                }
            }

            // build per-step affine maps and compose the lane's 4-step window
            Aff acc;
            {
                acc.m[0] = fmaf(c1[0][0], a[0], 1.f); acc.m[1] = c1[0][0] * a[1]; acc.m[2] = c1[0][0] * a[2];
                acc.m[3] = c1[0][1] * a[3]; acc.m[4] = fmaf(c1[0][1], a[4], 1.f); acc.m[5] = c1[0][1] * a[5];
                acc.m[6] = c1[0][2] * a[6]; acc.m[7] = c1[0][2] * a[7]; acc.m[8] = fmaf(c1[0][2], a[8], 1.f);
                acc.b[0] = cb[0][0]; acc.b[1] = cb[0][1]; acc.b[2] = cb[0][2];
            }
#pragma unroll
            for (int i = 1; i < M; ++i) {
                Aff s, r;
                s.m[0] = fmaf(c1[i][0], a[0], 1.f); s.m[1] = c1[i][0] * a[1]; s.m[2] = c1[i][0] * a[2];
                s.m[3] = c1[i][1] * a[3]; s.m[4] = fmaf(c1[i][1], a[4], 1.f); s.m[5] = c1[i][1] * a[5];
                s.m[6] = c1[i][2] * a[6]; s.m[7] = c1[i][2] * a[7]; s.m[8] = fmaf(c1[i][2], a[8], 1.f);
                s.b[0] = cb[i][0]; s.b[1] = cb[i][1]; s.b[2] = cb[i][2];
                compose(r, s, acc); acc = r;
            }

            // 64-lane affine scan (inclusive, non-commutative compose)
            scan_level<0x111, 0xf>(acc);
            scan_level<0x112, 0xf>(acc);
            scan_level<0x114, 0xf>(acc);
            scan_level<0x118, 0xf>(acc);
            scan_level<0x142, 0xa>(acc);
            scan_level<0x143, 0xc>(acc);

            // window-start delta (delta at group start = 0 -> window end = acc.b)
            float ds0 = __shfl_up(acc.b[0], 1, 64);
            float ds1 = __shfl_up(acc.b[1], 1, 64);
            float ds2 = __shfl_up(acc.b[2], 1, 64);
            if (lane == 0) { ds0 = 0.f; ds1 = 0.f; ds2 = 0.f; }

            // in-lane forward reconstruction with 2nd+3rd-order Taylor terms
            float d0 = ds0, d1 = ds1, d2 = ds2;
            float douts[M][3];
#pragma unroll
            for (int i = 0; i < M; ++i) {
                float zz0 = fmaf(a[0], d0, fmaf(a[1], d1, a[2] * d2));
                float zz1 = fmaf(a[3], d0, fmaf(a[4], d1, a[5] * d2));
                float zz2 = fmaf(a[6], d0, fmaf(a[7], d1, a[8] * d2));
                d0 += fmaf(fmaf(fmaf(cT3[i][0], zz0, cT2[i][0]), zz0, c1[i][0]), zz0, cb[i][0]);
                d1 += fmaf(fmaf(fmaf(cT3[i][1], zz1, cT2[i][1]), zz1, c1[i][1]), zz1, cb[i][1]);
                d2 += fmaf(fmaf(fmaf(cT3[i][2], zz2, cT2[i][2]), zz2, c1[i][2]), zz2, cb[i][2]);
                douts[i][0] = d0; douts[i][1] = d1; douts[i][2] = d2;
            }

            // per-window nonlinear defect = poly-forward end - linear-scan end;
            // exclusive float-scan propagates defects across windows (~identity)
            float q0 = d0 - acc.b[0], q1 = d1 - acc.b[1], q2 = d2 - acc.b[2];
            float e0 = wave_incl_scan(q0) - q0;
            float e1 = wave_incl_scan(q1) - q1;
            float e2 = wave_incl_scan(q2) - q2;
            float cor0 = x0 + e0, cor1 = x1 + e1, cor2 = x2 + e2;

            const int base = gg * K + M * lane;
            float4 s0 = { douts[0][0] + cor0, douts[1][0] + cor0, douts[2][0] + cor0, douts[3][0] + cor0 };
            float4 s1 = { douts[0][1] + cor1, douts[1][1] + cor1, douts[2][1] + cor1, douts[3][1] + cor1 };
            float4 s2 = { douts[0][2] + cor2, douts[1][2] + cor2, douts[2][2] + cor2, douts[3][2] + cor2 };
            *(float4*)&xs[base]               = s0;
            *(float4*)&xs[SEQ_LEN + base]     = s1;
            *(float4*)&xs[2 * SEQ_LEN + base] = s2;

            // handoff: lane 63's last output is the next group-start state
            x0 = readlane_f(s0.w, 63);
            x1 = readlane_f(s1.w, 63);
            x2 = readlane_f(s2.w, 63);
        }
    }
}

// ---------- kernel 3: pointwise MLP (parallel) ----------
__global__ __launch_bounds__(256) void mlp_kernel(
    const float* __restrict__ xs, const float* __restrict__ W1,
    const float* __restrict__ b1v, const float* __restrict__ W2,
    const float* __restrict__ b2v, float* __restrict__ out) {
    int s = blockIdx.x * 256 + threadIdx.x;
    float x0 = xs[s], x1 = xs[SEQ_LEN + s], x2 = xs[2 * SEQ_LEN + s];
    float acc0 = 0.f, acc1 = 0.f, acc2 = 0.f;
#pragma unroll 4
    for (int h = 0; h < HID; ++h) {
        float hv = fmaf(W1[3 * h + 0], x0,
                   fmaf(W1[3 * h + 1], x1,
                   fmaf(W1[3 * h + 2], x2, b1v[h])));
        hv = fmaxf(hv, 0.f);
        acc0 = fmaf(W2[h], hv, acc0);
        acc1 = fmaf(W2[HID + h], hv, acc1);
        acc2 = fmaf(W2[2 * HID + h], hv, acc2);
    }
    out[s] = acc0 + b2v[0];
    out[SEQ_LEN + s] = acc1 + b2v[1];
    out[2 * SEQ_LEN + s] = acc2 + b2v[2];
}

extern "C" void kernel_launch(void* const* d_in, const int* in_sizes, int n_in,
                              void* d_out, int out_size, void* d_ws, size_t ws_size,
                              hipStream_t stream) {
    const float* u  = (const float*)d_in[0];
    const float* dt = (const float*)d_in[1];
    const float* A  = (const float*)d_in[2];
    const float* B  = (const float*)d_in[3];
    const float* bA = (const float*)d_in[4];
    const float* W1 = (const float*)d_in[5];
    const float* b1 = (const float*)d_in[6];
    const float* W2 = (const float*)d_in[7];
    const float* b2 = (const float*)d_in[8];

    float* out  = (float*)d_out;
    float* memb = out + 3 * SEQ_LEN;
    float4* v   = (float4*)d_ws;   // 4 MB scratch

    vprep_kernel<<<SEQ_LEN / 256, 256, 0, stream>>>(u, B, bA, v);
    scan_kernel<<<1, 64, 0, stream>>>(v, A, dt, memb);
    mlp_kernel<<<SEQ_LEN / 256, 256, 0, stream>>>(memb, W1, b1, W2, b2, out);
}

// Round 4
// 1322.131 us; speedup vs baseline: 1.5589x; 1.1778x over previous
//
#include <hip/hip_runtime.h>

#define SEQ_LEN 262144
#define K 512                      // steps per group (one wave)
#define M 8                        // steps per lane (in-lane serial window)
#define NG (SEQ_LEN / K)           // 512 groups
#define PF 2                       // prefetch ring depth (groups)
#define HID 256
#define C2LE 2.885390081777927f    // 2*log2(e)

// ---------- DPP helpers ----------
template <int CTRL, int RM>
__device__ __forceinline__ float dpp_mov(float oldv, float v) {
    return __builtin_bit_cast(float, __builtin_amdgcn_update_dpp(
        __builtin_bit_cast(int, oldv), __builtin_bit_cast(int, v), CTRL, RM, 0xf, false));
}
template <int CTRL, int RM>
__device__ __forceinline__ float dpp_add(float v) {
    return v + dpp_mov<CTRL, RM>(0.0f, v);
}
__device__ __forceinline__ float wave_incl_scan(float v) {
    v = dpp_add<0x111, 0xf>(v);  // row_shr:1
    v = dpp_add<0x112, 0xf>(v);  // row_shr:2
    v = dpp_add<0x114, 0xf>(v);  // row_shr:4
    v = dpp_add<0x118, 0xf>(v);  // row_shr:8
    v = dpp_add<0x142, 0xa>(v);  // row_bcast:15 -> rows 1,3
    v = dpp_add<0x143, 0xc>(v);  // row_bcast:31 -> rows 2,3
    return v;
}
// full-wave shift right by 1 (lane i <- lane i-1; lane0 <- 0)
__device__ __forceinline__ float dpp_wshr1(float v) {
    return __builtin_bit_cast(float, __builtin_amdgcn_update_dpp(
        0, __builtin_bit_cast(int, v), 0x138, 0xf, 0xf, false));
}
__device__ __forceinline__ float readlane_f(float v, int lane) {
    return __builtin_bit_cast(
        float, __builtin_amdgcn_readlane(__builtin_bit_cast(int, v), lane));
}

// ---------- affine map (3x3 M, 3 b) ----------
struct Aff { float m[9]; float b[3]; };

// r = n ∘ o  (apply o first, then n)
__device__ __forceinline__ void compose(Aff& r, const Aff& n, const Aff& o) {
#pragma unroll
    for (int i = 0; i < 3; ++i) {
#pragma unroll
        for (int j = 0; j < 3; ++j)
            r.m[3*i+j] = fmaf(n.m[3*i+0], o.m[0+j],
                         fmaf(n.m[3*i+1], o.m[3+j],
                              n.m[3*i+2] * o.m[6+j]));
        r.b[i] = fmaf(n.m[3*i+0], o.b[0],
                 fmaf(n.m[3*i+1], o.b[1],
                 fmaf(n.m[3*i+2], o.b[2], n.b[i])));
    }
}

// one Hillis-Steele level: partner fetched via DPP with identity as `old`
template <int CTRL, int RM>
__device__ __forceinline__ void scan_level(Aff& a) {
    Aff p;
    p.m[0] = dpp_mov<CTRL, RM>(1.f, a.m[0]);
    p.m[1] = dpp_mov<CTRL, RM>(0.f, a.m[1]);
    p.m[2] = dpp_mov<CTRL, RM>(0.f, a.m[2]);
    p.m[3] = dpp_mov<CTRL, RM>(0.f, a.m[3]);
    p.m[4] = dpp_mov<CTRL, RM>(1.f, a.m[4]);
    p.m[5] = dpp_mov<CTRL, RM>(0.f, a.m[5]);
    p.m[6] = dpp_mov<CTRL, RM>(0.f, a.m[6]);
    p.m[7] = dpp_mov<CTRL, RM>(0.f, a.m[7]);
    p.m[8] = dpp_mov<CTRL, RM>(1.f, a.m[8]);
    p.b[0] = dpp_mov<CTRL, RM>(0.f, a.b[0]);
    p.b[1] = dpp_mov<CTRL, RM>(0.f, a.b[1]);
    p.b[2] = dpp_mov<CTRL, RM>(0.f, a.b[2]);
    Aff r; compose(r, a, p); a = r;
}

// ---------- kernel 1: w_t = C2LE*(B u_t + bA), packed float4 ----------
__global__ __launch_bounds__(256) void vprep_kernel(
    const float* __restrict__ u, const float* __restrict__ B,
    const float* __restrict__ bA, float4* __restrict__ v) {
    int s = blockIdx.x * 256 + threadIdx.x;
    float u0 = u[s], u1 = u[SEQ_LEN + s], u2 = u[2 * SEQ_LEN + s];
    float4 o;
    o.x = C2LE * fmaf(B[0], u0, fmaf(B[1], u1, fmaf(B[2], u2, bA[0])));
    o.y = C2LE * fmaf(B[3], u0, fmaf(B[4], u1, fmaf(B[5], u2, bA[1])));
    o.z = C2LE * fmaf(B[6], u0, fmaf(B[7], u1, fmaf(B[8], u2, bA[2])));
    o.w = 0.f;
    v[s] = o;
}

// ---------- kernel 2: serial affine-scan, 1 wave, 512 steps/group ----------
__global__ __launch_bounds__(64, 1) void scan_kernel(
    const float4* __restrict__ v,  // [S] C2LE-scaled w
    const float* __restrict__ Am,  // [3][3]
    const float* __restrict__ dtp, // scalar
    float* __restrict__ xs) {      // [3][S]
    const int lane = threadIdx.x;
    const float dt = dtp[0];
    const float invdt3 = 1.0f / (3.0f * dt);
    float a[9], as[9];
#pragma unroll
    for (int i = 0; i < 9; ++i) { a[i] = Am[i]; as[i] = C2LE * Am[i]; }

    float x0 = 0.f, x1 = 0.f, x2 = 0.f;  // group-start state (wave-uniform)

    // prefetch ring: lane j holds M consecutive float4s (128B contiguous)
    float4 rb[PF][M];
#pragma unroll
    for (int p = 0; p < PF; ++p)
#pragma unroll
        for (int i = 0; i < M; ++i)
            rb[p][i] = v[p * K + M * lane + i];

    for (int g = 0; g < NG; g += PF) {
#pragma unroll
        for (int p = 0; p < PF; ++p) {
            const int gg = g + p;

            // zc = C2LE * A * x_g (wave-uniform)
            float zc0 = fmaf(as[0], x0, fmaf(as[1], x1, as[2] * x2));
            float zc1 = fmaf(as[3], x0, fmaf(as[4], x1, as[5] * x2));
            float zc2 = fmaf(as[6], x0, fmaf(as[7], x1, as[8] * x2));

            // coefficient phase: ONE tanh per step-channel; store t0, c1 only
            float t0s[M][3], c1s[M][3];
            Aff acc;
#pragma unroll
            for (int i = 0; i < M; ++i) {
                float4 wv = rb[p][i];
                float z[3] = { wv.x + zc0, wv.y + zc1, wv.z + zc2 };
                float cb[3], cv[3];
#pragma unroll
                for (int c = 0; c < 3; ++c) {
                    float e  = __builtin_amdgcn_exp2f(z[c]);
                    float r  = __builtin_amdgcn_rcpf(e + 1.0f);
                    float t  = fmaf(-2.0f, r, 1.0f);     // tanh
                    float b  = dt * t;
                    float c1 = fmaf(-b, t, dt);          // dt*(1-t^2)
                    t0s[i][c] = t; c1s[i][c] = c1;
                    cb[c] = b; cv[c] = c1;
                }
                // step map: M = I + diag(cv)*A ; b = cb
                Aff s;
                s.m[0] = fmaf(cv[0], a[0], 1.f); s.m[1] = cv[0] * a[1]; s.m[2] = cv[0] * a[2];
                s.m[3] = cv[1] * a[3]; s.m[4] = fmaf(cv[1], a[4], 1.f); s.m[5] = cv[1] * a[5];
                s.m[6] = cv[2] * a[6]; s.m[7] = cv[2] * a[7]; s.m[8] = fmaf(cv[2], a[8], 1.f);
                s.b[0] = cb[0]; s.b[1] = cb[1]; s.b[2] = cb[2];
                if (i == 0) acc = s;
                else { Aff r; compose(r, s, acc); acc = r; }
            }

            // prefetch group gg+PF (wrap to 0 at tail; harmless dummy)
            {
                int ng = (gg + PF < NG) ? (gg + PF) : 0;
#pragma unroll
                for (int i = 0; i < M; ++i) rb[p][i] = v[ng * K + M * lane + i];
            }

            // 64-lane affine scan (inclusive, non-commutative compose)
            scan_level<0x111, 0xf>(acc);
            scan_level<0x112, 0xf>(acc);
            scan_level<0x114, 0xf>(acc);
            scan_level<0x118, 0xf>(acc);
            scan_level<0x142, 0xa>(acc);
            scan_level<0x143, 0xc>(acc);

            // window-start delta via full-wave DPP shift (lane0 -> 0)
            float ds0 = dpp_wshr1(acc.b[0]);
            float ds1 = dpp_wshr1(acc.b[1]);
            float ds2 = dpp_wshr1(acc.b[2]);

            // in-lane forward reconstruction, 3rd-order Taylor (coeffs rebuilt)
            float d0 = ds0, d1 = ds1, d2 = ds2;
            float outv[M][3];
#pragma unroll
            for (int i = 0; i < M; ++i) {
                float zz0 = fmaf(a[0], d0, fmaf(a[1], d1, a[2] * d2));
                float zz1 = fmaf(a[3], d0, fmaf(a[4], d1, a[5] * d2));
                float zz2 = fmaf(a[6], d0, fmaf(a[7], d1, a[8] * d2));
                float zz[3] = { zz0, zz1, zz2 };
                float dd[3];
#pragma unroll
                for (int c = 0; c < 3; ++c) {
                    float t   = t0s[i][c], cv = c1s[i][c];
                    float cb  = dt * t;
                    float cT2 = -(t * cv);                               // -dt*T0*T1
                    float pc  = fmaf(-invdt3, cv, 0.66666667f * (t * t));
                    float cT3 = cv * pc;
                    dd[c] = fmaf(fmaf(fmaf(cT3, zz[c], cT2), zz[c], cv), zz[c], cb);
                }
                d0 += dd[0]; d1 += dd[1]; d2 += dd[2];
                outv[i][0] = d0; outv[i][1] = d1; outv[i][2] = d2;
            }

            // per-window nonlinear defect; exclusive float-scan propagates
            float q0 = d0 - acc.b[0], q1 = d1 - acc.b[1], q2 = d2 - acc.b[2];
            float e0 = wave_incl_scan(q0) - q0;
            float e1 = wave_incl_scan(q1) - q1;
            float e2 = wave_incl_scan(q2) - q2;
            float cor0 = x0 + e0, cor1 = x1 + e1, cor2 = x2 + e2;

            const int base = gg * K + M * lane;
            float4 s0a = { outv[0][0] + cor0, outv[1][0] + cor0, outv[2][0] + cor0, outv[3][0] + cor0 };
            float4 s0b = { outv[4][0] + cor0, outv[5][0] + cor0, outv[6][0] + cor0, outv[7][0] + cor0 };
            float4 s1a = { outv[0][1] + cor1, outv[1][1] + cor1, outv[2][1] + cor1, outv[3][1] + cor1 };
            float4 s1b = { outv[4][1] + cor1, outv[5][1] + cor1, outv[6][1] + cor1, outv[7][1] + cor1 };
            float4 s2a = { outv[0][2] + cor2, outv[1][2] + cor2, outv[2][2] + cor2, outv[3][2] + cor2 };
            float4 s2b = { outv[4][2] + cor2, outv[5][2] + cor2, outv[6][2] + cor2, outv[7][2] + cor2 };
            *(float4*)&xs[base]                   = s0a;
            *(float4*)&xs[base + 4]               = s0b;
            *(float4*)&xs[SEQ_LEN + base]         = s1a;
            *(float4*)&xs[SEQ_LEN + base + 4]     = s1b;
            *(float4*)&xs[2 * SEQ_LEN + base]     = s2a;
            *(float4*)&xs[2 * SEQ_LEN + base + 4] = s2b;

            // handoff: lane 63's last output is the next group-start state
            x0 = readlane_f(s0b.w, 63);
            x1 = readlane_f(s1b.w, 63);
            x2 = readlane_f(s2b.w, 63);
        }
    }
}

// ---------- kernel 3: pointwise MLP (parallel) ----------
__global__ __launch_bounds__(256) void mlp_kernel(
    const float* __restrict__ xs, const float* __restrict__ W1,
    const float* __restrict__ b1v, const float* __restrict__ W2,
    const float* __restrict__ b2v, float* __restrict__ out) {
    int s = blockIdx.x * 256 + threadIdx.x;
    float x0 = xs[s], x1 = xs[SEQ_LEN + s], x2 = xs[2 * SEQ_LEN + s];
    float acc0 = 0.f, acc1 = 0.f, acc2 = 0.f;
#pragma unroll 4
    for (int h = 0; h < HID; ++h) {
        float hv = fmaf(W1[3 * h + 0], x0,
                   fmaf(W1[3 * h + 1], x1,
                   fmaf(W1[3 * h + 2], x2, b1v[h])));
        hv = fmaxf(hv, 0.f);
        acc0 = fmaf(W2[h], hv, acc0);
        acc1 = fmaf(W2[HID + h], hv, acc1);
        acc2 = fmaf(W2[2 * HID + h], hv, acc2);
    }
    out[s] = acc0 + b2v[0];
    out[SEQ_LEN + s] = acc1 + b2v[1];
    out[2 * SEQ_LEN + s] = acc2 + b2v[2];
}

extern "C" void kernel_launch(void* const* d_in, const int* in_sizes, int n_in,
                              void* d_out, int out_size, void* d_ws, size_t ws_size,
                              hipStream_t stream) {
    const float* u  = (const float*)d_in[0];
    const float* dt = (const float*)d_in[1];
    const float* A  = (const float*)d_in[2];
    const float* B  = (const float*)d_in[3];
    const float* bA = (const float*)d_in[4];
    const float* W1 = (const float*)d_in[5];
    const float* b1 = (const float*)d_in[6];
    const float* W2 = (const float*)d_in[7];
    const float* b2 = (const float*)d_in[8];

    float* out  = (float*)d_out;
    float* memb = out + 3 * SEQ_LEN;
    float4* v   = (float4*)d_ws;   // 4 MB scratch

    vprep_kernel<<<SEQ_LEN / 256, 256, 0, stream>>>(u, B, bA, v);
    scan_kernel<<<1, 64, 0, stream>>>(v, A, dt, memb);
    mlp_kernel<<<SEQ_LEN / 256, 256, 0, stream>>>(memb, W1, b1, W2, b2, out);
}

// Round 5
// 178.890 us; speedup vs baseline: 11.5211x; 7.3908x over previous
//
#include <hip/hip_runtime.h>

#define SEQ_LEN 262144
#define K 512                      // steps per group (one wave shoots one group)
#define M 8                        // steps per lane
#define NG (SEQ_LEN / K)           // 512 groups
#define NITER 10                   // Newton iterations
#define HID 256
#define C2LE 2.885390081777927f    // 2*log2(e)

// ---------- DPP helpers ----------
template <int CTRL, int RM>
__device__ __forceinline__ float dpp_mov(float oldv, float v) {
    return __builtin_bit_cast(float, __builtin_amdgcn_update_dpp(
        __builtin_bit_cast(int, oldv), __builtin_bit_cast(int, v), CTRL, RM, 0xf, false));
}
template <int CTRL, int RM>
__device__ __forceinline__ float dpp_add(float v) {
    return v + dpp_mov<CTRL, RM>(0.0f, v);
}
__device__ __forceinline__ float wave_incl_scan(float v) {
    v = dpp_add<0x111, 0xf>(v);
    v = dpp_add<0x112, 0xf>(v);
    v = dpp_add<0x114, 0xf>(v);
    v = dpp_add<0x118, 0xf>(v);
    v = dpp_add<0x142, 0xa>(v);
    v = dpp_add<0x143, 0xc>(v);
    return v;
}
// full-wave shift right by 1 (lane i <- lane i-1; lane0 <- 0)
__device__ __forceinline__ float dpp_wshr1(float v) {
    return __builtin_bit_cast(float, __builtin_amdgcn_update_dpp(
        0, __builtin_bit_cast(int, v), 0x138, 0xf, 0xf, false));
}
__device__ __forceinline__ float readlane_f(float v, int lane) {
    return __builtin_bit_cast(
        float, __builtin_amdgcn_readlane(__builtin_bit_cast(int, v), lane));
}

// ---------- affine map (3x3 M, 3 b) ----------
struct Aff { float m[9]; float b[3]; };

// r = n ∘ o  (apply o first, then n)
__device__ __forceinline__ void compose(Aff& r, const Aff& n, const Aff& o) {
#pragma unroll
    for (int i = 0; i < 3; ++i) {
#pragma unroll
        for (int j = 0; j < 3; ++j)
            r.m[3*i+j] = fmaf(n.m[3*i+0], o.m[0+j],
                         fmaf(n.m[3*i+1], o.m[3+j],
                              n.m[3*i+2] * o.m[6+j]));
        r.b[i] = fmaf(n.m[3*i+0], o.b[0],
                 fmaf(n.m[3*i+1], o.b[1],
                 fmaf(n.m[3*i+2], o.b[2], n.b[i])));
    }
}

template <int CTRL, int RM>
__device__ __forceinline__ void scan_level(Aff& a) {
    Aff p;
    p.m[0] = dpp_mov<CTRL, RM>(1.f, a.m[0]);
    p.m[1] = dpp_mov<CTRL, RM>(0.f, a.m[1]);
    p.m[2] = dpp_mov<CTRL, RM>(0.f, a.m[2]);
    p.m[3] = dpp_mov<CTRL, RM>(0.f, a.m[3]);
    p.m[4] = dpp_mov<CTRL, RM>(1.f, a.m[4]);
    p.m[5] = dpp_mov<CTRL, RM>(0.f, a.m[5]);
    p.m[6] = dpp_mov<CTRL, RM>(0.f, a.m[6]);
    p.m[7] = dpp_mov<CTRL, RM>(0.f, a.m[7]);
    p.m[8] = dpp_mov<CTRL, RM>(1.f, a.m[8]);
    p.b[0] = dpp_mov<CTRL, RM>(0.f, a.b[0]);
    p.b[1] = dpp_mov<CTRL, RM>(0.f, a.b[1]);
    p.b[2] = dpp_mov<CTRL, RM>(0.f, a.b[2]);
    Aff r; compose(r, a, p); a = r;
}

// ---------- init: zero the group-start-state array ----------
__global__ __launch_bounds__(64) void init_kernel(float4* __restrict__ xh) {
    for (int i = threadIdx.x; i <= NG; i += 64)
        xh[i] = float4{0.f, 0.f, 0.f, 0.f};
}

// ---------- vprep: w_t = C2LE*(B u_t + bA), packed float4 ----------
__global__ __launch_bounds__(256) void vprep_kernel(
    const float* __restrict__ u, const float* __restrict__ B,
    const float* __restrict__ bA, float4* __restrict__ v) {
    int s = blockIdx.x * 256 + threadIdx.x;
    float u0 = u[s], u1 = u[SEQ_LEN + s], u2 = u[2 * SEQ_LEN + s];
    float4 o;
    o.x = C2LE * fmaf(B[0], u0, fmaf(B[1], u1, fmaf(B[2], u2, bA[0])));
    o.y = C2LE * fmaf(B[3], u0, fmaf(B[4], u1, fmaf(B[5], u2, bA[1])));
    o.z = C2LE * fmaf(B[6], u0, fmaf(B[7], u1, fmaf(B[8], u2, bA[2])));
    o.w = 0.f;
    v[s] = o;
}

// ---------- shoot: each block = one group, from guessed start xh[g] ----------
// STORE=false: emit J_g (group Jacobian) + F_g (group end state) to jf.
// STORE=true : write the within-group trajectory to xs.
template <bool STORE>
__global__ __launch_bounds__(64) void shoot_kernel(
    const float4* __restrict__ v,   // [S] C2LE-scaled w
    const float* __restrict__ Am,   // [3][3]
    const float* __restrict__ dtp,  // scalar
    const float4* __restrict__ xh,  // [NG+1] group start states
    float4* __restrict__ jf,        // [NG*3] {J[0..3]},{J[4..7]},{J8,F0,F1,F2}
    float* __restrict__ xs) {       // [3][S]
    const int lane = threadIdx.x;
    const int g = blockIdx.x;
    const float dt = dtp[0];
    const float invdt3 = 1.0f / (3.0f * dt);
    float a[9], as[9];
#pragma unroll
    for (int i = 0; i < 9; ++i) { a[i] = Am[i]; as[i] = C2LE * Am[i]; }

    float4 xg = xh[g];                       // wave-uniform broadcast load
    const float x0 = xg.x, x1 = xg.y, x2 = xg.z;

    float4 wv[M];
#pragma unroll
    for (int i = 0; i < M; ++i) wv[i] = v[g * K + M * lane + i];

    // zc = C2LE * A * x_g
    float zc0 = fmaf(as[0], x0, fmaf(as[1], x1, as[2] * x2));
    float zc1 = fmaf(as[3], x0, fmaf(as[4], x1, as[5] * x2));
    float zc2 = fmaf(as[6], x0, fmaf(as[7], x1, as[8] * x2));

    // coefficient phase: one tanh per step-channel; in-lane compose of 8 maps
    float t0s[M][3], c1s[M][3];
    Aff acc;
#pragma unroll
    for (int i = 0; i < M; ++i) {
        float z[3] = { wv[i].x + zc0, wv[i].y + zc1, wv[i].z + zc2 };
        float cb[3], cv[3];
#pragma unroll
        for (int c = 0; c < 3; ++c) {
            float e  = __builtin_amdgcn_exp2f(z[c]);
            float r  = __builtin_amdgcn_rcpf(e + 1.0f);
            float t  = fmaf(-2.0f, r, 1.0f);
            float b  = dt * t;
            float c1 = fmaf(-b, t, dt);
            t0s[i][c] = t; c1s[i][c] = c1;
            cb[c] = b; cv[c] = c1;
        }
        Aff s;
        s.m[0] = fmaf(cv[0], a[0], 1.f); s.m[1] = cv[0] * a[1]; s.m[2] = cv[0] * a[2];
        s.m[3] = cv[1] * a[3]; s.m[4] = fmaf(cv[1], a[4], 1.f); s.m[5] = cv[1] * a[5];
        s.m[6] = cv[2] * a[6]; s.m[7] = cv[2] * a[7]; s.m[8] = fmaf(cv[2], a[8], 1.f);
        s.b[0] = cb[0]; s.b[1] = cb[1]; s.b[2] = cb[2];
        if (i == 0) acc = s;
        else { Aff r; compose(r, s, acc); acc = r; }
    }

    // 64-lane affine scan
    scan_level<0x111, 0xf>(acc);
    scan_level<0x112, 0xf>(acc);
    scan_level<0x114, 0xf>(acc);
    scan_level<0x118, 0xf>(acc);
    scan_level<0x142, 0xa>(acc);
    scan_level<0x143, 0xc>(acc);

    // window-start delta
    float ds0 = dpp_wshr1(acc.b[0]);
    float ds1 = dpp_wshr1(acc.b[1]);
    float ds2 = dpp_wshr1(acc.b[2]);

    // in-lane forward reconstruction, 3rd-order Taylor
    float d0 = ds0, d1 = ds1, d2 = ds2;
    float outv[M][3];
#pragma unroll
    for (int i = 0; i < M; ++i) {
        float zz0 = fmaf(a[0], d0, fmaf(a[1], d1, a[2] * d2));
        float zz1 = fmaf(a[3], d0, fmaf(a[4], d1, a[5] * d2));
        float zz2 = fmaf(a[6], d0, fmaf(a[7], d1, a[8] * d2));
        float zz[3] = { zz0, zz1, zz2 };
        float dd[3];
#pragma unroll
        for (int c = 0; c < 3; ++c) {
            float t   = t0s[i][c], cv = c1s[i][c];
            float cb  = dt * t;
            float cT2 = -(t * cv);
            float pc  = fmaf(-invdt3, cv, 0.66666667f * (t * t));
            float cT3 = cv * pc;
            dd[c] = fmaf(fmaf(fmaf(cT3, zz[c], cT2), zz[c], cv), zz[c], cb);
        }
        d0 += dd[0]; d1 += dd[1]; d2 += dd[2];
        outv[i][0] = d0; outv[i][1] = d1; outv[i][2] = d2;
    }

    // per-window nonlinear defect; exclusive float-scan propagates
    float q0 = d0 - acc.b[0], q1 = d1 - acc.b[1], q2 = d2 - acc.b[2];
    float e0 = wave_incl_scan(q0) - q0;
    float e1 = wave_incl_scan(q1) - q1;
    float e2 = wave_incl_scan(q2) - q2;
    float cor0 = x0 + e0, cor1 = x1 + e1, cor2 = x2 + e2;

    if (STORE) {
        const int base = g * K + M * lane;
        float4 s0a = { outv[0][0] + cor0, outv[1][0] + cor0, outv[2][0] + cor0, outv[3][0] + cor0 };
        float4 s0b = { outv[4][0] + cor0, outv[5][0] + cor0, outv[6][0] + cor0, outv[7][0] + cor0 };
        float4 s1a = { outv[0][1] + cor1, outv[1][1] + cor1, outv[2][1] + cor1, outv[3][1] + cor1 };
        float4 s1b = { outv[4][1] + cor1, outv[5][1] + cor1, outv[6][1] + cor1, outv[7][1] + cor1 };
        float4 s2a = { outv[0][2] + cor2, outv[1][2] + cor2, outv[2][2] + cor2, outv[3][2] + cor2 };
        float4 s2b = { outv[4][2] + cor2, outv[5][2] + cor2, outv[6][2] + cor2, outv[7][2] + cor2 };
        *(float4*)&xs[base]                   = s0a;
        *(float4*)&xs[base + 4]               = s0b;
        *(float4*)&xs[SEQ_LEN + base]         = s1a;
        *(float4*)&xs[SEQ_LEN + base + 4]     = s1b;
        *(float4*)&xs[2 * SEQ_LEN + base]     = s2a;
        *(float4*)&xs[2 * SEQ_LEN + base + 4] = s2b;
    } else {
        // lane 63 holds the full-group Jacobian (acc.m) and end state
        if (lane == 63) {
            float F0 = outv[M-1][0] + cor0;
            float F1 = outv[M-1][1] + cor1;
            float F2 = outv[M-1][2] + cor2;
            jf[3*g + 0] = float4{ acc.m[0], acc.m[1], acc.m[2], acc.m[3] };
            jf[3*g + 1] = float4{ acc.m[4], acc.m[5], acc.m[6], acc.m[7] };
            jf[3*g + 2] = float4{ acc.m[8], F0, F1, F2 };
        }
    }
}

// ---------- correct: Newton update across groups = 512-elem affine scan ----------
__global__ __launch_bounds__(64) void correct_kernel(
    const float4* __restrict__ jf, float4* __restrict__ xh) {
    const int lane = threadIdx.x;
    float J[8][9], d[8][3];
    float4 xn[8];
#pragma unroll
    for (int i = 0; i < 8; ++i) {
        int g = 8 * lane + i;
        float4 q0 = jf[3*g + 0], q1 = jf[3*g + 1], q2 = jf[3*g + 2];
        xn[i] = xh[g + 1];
        J[i][0] = q0.x; J[i][1] = q0.y; J[i][2] = q0.z; J[i][3] = q0.w;
        J[i][4] = q1.x; J[i][5] = q1.y; J[i][6] = q1.z; J[i][7] = q1.w;
        J[i][8] = q2.x;
        d[i][0] = q2.y - xn[i].x;   // F_g - xh_old[g+1]
        d[i][1] = q2.z - xn[i].y;
        d[i][2] = q2.w - xn[i].z;
    }
    // in-lane compose of 8 group maps (earliest first)
    Aff acc;
#pragma unroll
    for (int i = 0; i < 9; ++i) acc.m[i] = J[0][i];
    acc.b[0] = d[0][0]; acc.b[1] = d[0][1]; acc.b[2] = d[0][2];
#pragma unroll
    for (int i = 1; i < 8; ++i) {
        Aff s;
#pragma unroll
        for (int k = 0; k < 9; ++k) s.m[k] = J[i][k];
        s.b[0] = d[i][0]; s.b[1] = d[i][1]; s.b[2] = d[i][2];
        Aff r; compose(r, s, acc); acc = r;
    }
    // 64-lane scan
    scan_level<0x111, 0xf>(acc);
    scan_level<0x112, 0xf>(acc);
    scan_level<0x114, 0xf>(acc);
    scan_level<0x118, 0xf>(acc);
    scan_level<0x142, 0xa>(acc);
    scan_level<0x143, 0xc>(acc);
    // window-start correction (e at first group of this lane's window)
    float e0 = dpp_wshr1(acc.b[0]);
    float e1 = dpp_wshr1(acc.b[1]);
    float e2 = dpp_wshr1(acc.b[2]);
    // rewalk window: e_{g+1} = d_g + J_g e_g ; update xh[g+1]
#pragma unroll
    for (int i = 0; i < 8; ++i) {
        float n0 = fmaf(J[i][0], e0, fmaf(J[i][1], e1, fmaf(J[i][2], e2, d[i][0])));
        float n1 = fmaf(J[i][3], e0, fmaf(J[i][4], e1, fmaf(J[i][5], e2, d[i][1])));
        float n2 = fmaf(J[i][6], e0, fmaf(J[i][7], e1, fmaf(J[i][8], e2, d[i][2])));
        e0 = n0; e1 = n1; e2 = n2;
        int g = 8 * lane + i;
        xh[g + 1] = float4{ xn[i].x + e0, xn[i].y + e1, xn[i].z + e2, 0.f };
    }
}

// ---------- MLP (parallel) ----------
__global__ __launch_bounds__(256) void mlp_kernel(
    const float* __restrict__ xs, const float* __restrict__ W1,
    const float* __restrict__ b1v, const float* __restrict__ W2,
    const float* __restrict__ b2v, float* __restrict__ out) {
    int s = blockIdx.x * 256 + threadIdx.x;
    float x0 = xs[s], x1 = xs[SEQ_LEN + s], x2 = xs[2 * SEQ_LEN + s];
    float acc0 = 0.f, acc1 = 0.f, acc2 = 0.f;
#pragma unroll 4
    for (int h = 0; h < HID; ++h) {
        float hv = fmaf(W1[3 * h + 0], x0,
                   fmaf(W1[3 * h + 1], x1,
                   fmaf(W1[3 * h + 2], x2, b1v[h])));
        hv = fmaxf(hv, 0.f);
        acc0 = fmaf(W2[h], hv, acc0);
        acc1 = fmaf(W2[HID + h], hv, acc1);
        acc2 = fmaf(W2[2 * HID + h], hv, acc2);
    }
    out[s] = acc0 + b2v[0];
    out[SEQ_LEN + s] = acc1 + b2v[1];
    out[2 * SEQ_LEN + s] = acc2 + b2v[2];
}

extern "C" void kernel_launch(void* const* d_in, const int* in_sizes, int n_in,
                              void* d_out, int out_size, void* d_ws, size_t ws_size,
                              hipStream_t stream) {
    const float* u  = (const float*)d_in[0];
    const float* dt = (const float*)d_in[1];
    const float* A  = (const float*)d_in[2];
    const float* B  = (const float*)d_in[3];
    const float* bA = (const float*)d_in[4];
    const float* W1 = (const float*)d_in[5];
    const float* b1 = (const float*)d_in[6];
    const float* W2 = (const float*)d_in[7];
    const float* b2 = (const float*)d_in[8];

    float* out  = (float*)d_out;
    float* memb = out + 3 * SEQ_LEN;

    float4* v  = (float4*)d_ws;          // [S]      4 MB
    float4* xh = v + SEQ_LEN;            // [NG+1]   8.2 KB
    float4* jf = xh + (NG + 1);          // [NG*3]   24.6 KB

    init_kernel<<<1, 64, 0, stream>>>(xh);
    vprep_kernel<<<SEQ_LEN / 256, 256, 0, stream>>>(u, B, bA, v);
    for (int it = 0; it < NITER; ++it) {
        shoot_kernel<false><<<NG, 64, 0, stream>>>(v, A, dt, xh, jf, nullptr);
        correct_kernel<<<1, 64, 0, stream>>>(jf, xh);
    }
    shoot_kernel<true><<<NG, 64, 0, stream>>>(v, A, dt, xh, nullptr, memb);
    mlp_kernel<<<SEQ_LEN / 256, 256, 0, stream>>>(memb, W1, b1, W2, b2, out);
}